// Round 5
// baseline (15698.360 us; speedup 1.0000x reference)
//
#include <hip/hip_runtime.h>

// Qwen3 attention block, MI355X gfx950.
// Round 5: OUTPUT DTYPE FIX. Round 4's bisection: naive fp32 VALU path gave
// absmax 5.828 vs MFMA pipeline's 5.844 -- two independent engines, same
// error => shared I/O assumption wrong. Inputs exonerated (round-2 NaN vs
// round-3 finite differential). Culprit: outputs are FP32 (reference computes
// fp32 end-to-end; harness reads the reference's output dtype), not bf16 --
// my "bf16 out" inference came from a code snippet that shows every readback
// branch. This round: identical bisection structure, all outputs fp32.
//   Output 0 (out): naive fp32 VALU path (semantics test)
//   Output 1 (k):   MFMA gemm_nt -> norm_rope (gemm_nt layout test)
//   Output 2 (v):   naive GEMM (control)
// ws (24 MiB + 4 KiB): [0,4K) control {flag, qwc[128], kwc[128]}
//   [4K,+4M) kraw bf16 | [4K+4M,+4M) kqm bf16 | [4K+8M,+16M) attnbuf bf16
// d_out (fp32): out [0,8388608) | k [8388608,10485760) | v [10485760,12582912)
//   (bf16 q scratch borrows out's first 16 MiB; overwritten by final gemm)

typedef __bf16 bf16;
typedef __bf16 bf16x8 __attribute__((ext_vector_type(8)));
typedef float  f32x4  __attribute__((ext_vector_type(4)));

#define MFMA16(a, b, c) __builtin_amdgcn_mfma_f32_16x16x32_bf16((a), (b), (c), 0, 0, 0)

// ---------------------------------------------------------------- dtype probe
__global__ __launch_bounds__(256) void detect_convert(
    const unsigned short* __restrict__ probe,   // Wq bits
    const void* __restrict__ qw_raw, const void* __restrict__ kw_raw,
    int* __restrict__ flag, bf16* __restrict__ qwc, bf16* __restrict__ kwc) {
    __shared__ int cnt;
    if (threadIdx.x == 0) cnt = 0;
    __syncthreads();
    int local = 0;
    for (int i = 0; i < 4; ++i) {
        const unsigned short w = probe[(threadIdx.x * 4 + i) * 2];
        const int e = (w >> 7) & 0xFF;
        if (e >= 90 && e <= 140) ++local;
    }
    atomicAdd(&cnt, local);
    __syncthreads();
    const bool isbf16 = cnt >= 700;
    if (threadIdx.x == 0) *flag = isbf16 ? 1 : 0;
    const int t = threadIdx.x;
    if (t < 128)
        qwc[t] = isbf16 ? ((const bf16*)qw_raw)[t] : (bf16)((const float*)qw_raw)[t];
    else
        kwc[t - 128] = isbf16 ? ((const bf16*)kw_raw)[t - 128] : (bf16)((const float*)kw_raw)[t - 128];
}

// ---------------------------------------------------------------- MFMA GEMM (round-3 core, unchanged)
#define GBM 128
#define GBN 128
#define GBK 64
#define GLD 72

__global__ __launch_bounds__(256) void gemm_nt(const void* __restrict__ Av,
                                               const void* __restrict__ Bv,
                                               bf16* __restrict__ C,
                                               const int* __restrict__ flag,
                                               int aForceBf16,
                                               int M, int K,
                                               int ldb, int ldc, int col0) {
    __shared__ __align__(16) bf16 As[GBM * GLD];
    __shared__ __align__(16) bf16 Bs[GBN * GLD];
    const bool bBf16 = (*flag) != 0;
    const bool aBf16 = aForceBf16 || bBf16;
    const bf16*  Ab = (const bf16*)Av;
    const float* Af = (const float*)Av;
    const bf16*  Bb = (const bf16*)Bv;
    const float* Bf = (const float*)Bv;

    const int tid  = threadIdx.x;
    const int wave = tid >> 6;
    const int lane = tid & 63;
    const int l15  = lane & 15;
    const int quad = lane >> 4;
    const int m0 = blockIdx.y * GBM;
    const int n0 = blockIdx.x * GBN;
    const int wm = (wave >> 1) * 64;
    const int wn = (wave & 1) * 64;

    f32x4 acc[4][4];
    for (int i = 0; i < 4; ++i)
        for (int j = 0; j < 4; ++j) acc[i][j] = {0.f, 0.f, 0.f, 0.f};

    for (int k0 = 0; k0 < K; k0 += GBK) {
        for (int p = 0; p < 4; ++p) {
            const int c = p * 256 + tid;
            const int ar = c >> 3, ak = c & 7;
            const size_t aidx = (size_t)(m0 + ar) * K + k0 + ak * 8;
            bf16x8 avv;
            if (aBf16) {
                avv = *(const bf16x8*)&Ab[aidx];
            } else {
                const f32x4 a0 = *(const f32x4*)&Af[aidx];
                const f32x4 a1 = *(const f32x4*)&Af[aidx + 4];
                for (int e = 0; e < 4; ++e) { avv[e] = (bf16)a0[e]; avv[e + 4] = (bf16)a1[e]; }
            }
            *(bf16x8*)&As[ar * GLD + ak * 8] = avv;
            const int bk = c >> 4, bn = c & 15;
            const size_t bidx = (size_t)(k0 + bk) * ldb + n0 + bn * 8;
            bf16x8 bvv;
            if (bBf16) {
                bvv = *(const bf16x8*)&Bb[bidx];
            } else {
                const f32x4 b0 = *(const f32x4*)&Bf[bidx];
                const f32x4 b1 = *(const f32x4*)&Bf[bidx + 4];
                for (int e = 0; e < 4; ++e) { bvv[e] = (bf16)b0[e]; bvv[e + 4] = (bf16)b1[e]; }
            }
            for (int e = 0; e < 8; ++e) Bs[(bn * 8 + e) * GLD + bk] = bvv[e];
        }
        __syncthreads();
        for (int kk = 0; kk < GBK; kk += 32) {
            bf16x8 af[4], bfr[4];
            for (int i = 0; i < 4; ++i)
                af[i] = *(const bf16x8*)&As[(wm + i * 16 + l15) * GLD + kk + quad * 8];
            for (int j = 0; j < 4; ++j)
                bfr[j] = *(const bf16x8*)&Bs[(wn + j * 16 + l15) * GLD + kk + quad * 8];
            for (int i = 0; i < 4; ++i)
                for (int j = 0; j < 4; ++j)
                    acc[i][j] = MFMA16(af[i], bfr[j], acc[i][j]);
        }
        __syncthreads();
    }
    for (int i = 0; i < 4; ++i)
        for (int j = 0; j < 4; ++j)
            for (int r = 0; r < 4; ++r) {
                const int row = m0 + wm + i * 16 + quad * 4 + r;
                const int col = col0 + n0 + wn + j * 16 + l15;
                C[(size_t)row * ldc + col] = (bf16)acc[i][j][r];
            }
}

// ---------------------------------------------------------------- naive GEMM (fp32 accum, VALU)
// Writes bf16 (Cb) and/or fp32 (Cf). Grid covers M x N in 16x16 tiles.
__global__ __launch_bounds__(256) void naive_gemm(const void* __restrict__ Av,
                                                  const void* __restrict__ Bv,
                                                  bf16* __restrict__ Cb,
                                                  float* __restrict__ Cf,
                                                  const int* __restrict__ flag,
                                                  int aForce,
                                                  int K, int lda, int ldb, int ldc) {
    __shared__ float As[16][17], Bs[16][17];
    const int tx = threadIdx.x & 15, ty = threadIdx.x >> 4;
    const int row = blockIdx.y * 16 + ty, col = blockIdx.x * 16 + tx;
    const bool aB = aForce || (*flag) != 0;
    const bool bB = (*flag) != 0;
    float acc = 0.f;
    for (int k0 = 0; k0 < K; k0 += 16) {
        As[ty][tx] = aB ? (float)((const bf16*)Av)[(size_t)row * lda + k0 + tx]
                        : ((const float*)Av)[(size_t)row * lda + k0 + tx];
        Bs[ty][tx] = bB ? (float)((const bf16*)Bv)[(size_t)(k0 + ty) * ldb + col]
                        : ((const float*)Bv)[(size_t)(k0 + ty) * ldb + col];
        __syncthreads();
        for (int kk = 0; kk < 16; ++kk) acc += As[ty][kk] * Bs[kk][tx];
        __syncthreads();
    }
    if (Cb) Cb[(size_t)row * ldc + col] = (bf16)acc;
    if (Cf) Cf[(size_t)row * ldc + col] = acc;
}

// ---------------------------------------------------------------- norm + rope
// One wave per (token, head); src is [T][H][128] bf16. Writes bf16 (dst_bf,
// may alias src) and/or fp32 (dst_f32).
__global__ __launch_bounds__(256) void norm_rope(const bf16* __restrict__ src,
                                                 bf16* __restrict__ dst_bf,
                                                 float* __restrict__ dst_f32,
                                                 const bf16* __restrict__ w,
                                                 const int* __restrict__ positions,
                                                 int H) {
    const int wid  = blockIdx.x * 4 + (threadIdx.x >> 6);
    const int lane = threadIdx.x & 63;
    const int token = wid / H, head = wid % H;
    const bf16* s = src + ((size_t)token * H + head) * 128;
    const float f0 = (float)s[lane], f1 = (float)s[lane + 64];
    float ss = f0 * f0 + f1 * f1;
    for (int off = 32; off >= 1; off >>= 1) ss += __shfl_xor(ss, off);
    const float inv_rms = rsqrtf(ss * (1.0f / 128.0f) + 1e-6f);
    const float n0 = f0 * inv_rms * (float)w[lane];
    const float n1 = f1 * inv_rms * (float)w[lane + 64];
    const float pos = (float)positions[token];
    const float inv_ts = expf((float)lane * (-13.815510557964274f / 64.0f));
    const float ang = pos * inv_ts;
    const float sn = sinf(ang), cs = cosf(ang);
    const float o0 = n0 * cs - n1 * sn;
    const float o1 = n1 * cs + n0 * sn;
    const size_t base = ((size_t)token * H + head) * 128;
    if (dst_bf)  { dst_bf[base + lane] = (bf16)o0;  dst_bf[base + lane + 64] = (bf16)o1; }
    if (dst_f32) { dst_f32[base + lane] = o0;       dst_f32[base + lane + 64] = o1; }
}

// ---------------------------------------------------------------- naive attention
// One wave per (qrow, head). Q bf16; K,V fp32 (the final output buffers).
__global__ __launch_bounds__(256) void naive_attn(const bf16* __restrict__ Q,
                                                  const float* __restrict__ K,
                                                  const float* __restrict__ V,
                                                  bf16* __restrict__ O) {
    const int wid  = blockIdx.x * 4 + (threadIdx.x >> 6);  // 0..65535
    const int lane = threadIdx.x & 63;
    const int qrow = wid >> 5;
    const int h    = wid & 31;
    const int kvh  = h >> 2;
    const bf16* q = Q + ((size_t)qrow * 32 + h) * 128;
    const float q0 = (float)q[lane], q1 = (float)q[lane + 64];
    const float scale = 0.08838834764831845f;  // 1/sqrt(128)
    float m = -1e30f, s = 0.f, o0 = 0.f, o1 = 0.f;
    for (int key = 0; key <= qrow; ++key) {
        const float* kp = K + ((size_t)key * 8 + kvh) * 128;
        const float* vp = V + ((size_t)key * 8 + kvh) * 128;
        float d = q0 * kp[lane] + q1 * kp[lane + 64];
        for (int off = 32; off >= 1; off >>= 1) d += __shfl_xor(d, off);
        d *= scale;
        const float mn = fmaxf(m, d);
        const float corr = __expf(m - mn);
        const float p = __expf(d - mn);
        s  = s * corr + p;
        o0 = o0 * corr + p * vp[lane];
        o1 = o1 * corr + p * vp[lane + 64];
        m = mn;
    }
    O[(size_t)qrow * 4096 + h * 128 + lane]      = (bf16)(o0 / s);
    O[(size_t)qrow * 4096 + h * 128 + lane + 64] = (bf16)(o1 / s);
}

// ---------------------------------------------------------------- launch
extern "C" void kernel_launch(void* const* d_in, const int* in_sizes, int n_in,
                              void* d_out, int out_size, void* d_ws, size_t ws_size,
                              hipStream_t stream) {
    const void* x  = d_in[0];   // [2048][4096]  fp32 (auto-detected)
    const void* Wq = d_in[1];   // [4096][4096]
    const void* Wk = d_in[2];   // [4096][1024]
    const void* Wv = d_in[3];   // [4096][1024]
    const void* Wo = d_in[4];   // [4096][4096]
    const void* qw = d_in[5];   // [128]
    const void* kw = d_in[6];   // [128]
    const int* positions = (const int*)d_in[8];

    char* ws = (char*)d_ws;
    int*  flag    = (int*)ws;
    bf16* qwc     = (bf16*)(ws + 64);
    bf16* kwc     = (bf16*)(ws + 64 + 256);
    bf16* kraw    = (bf16*)(ws + 4096);                 // [2048][8][128] naive k pre-norm
    bf16* kqm     = (bf16*)(ws + 4096 + 4194304);       // [2048][8][128] MFMA k pre-norm
    bf16* attnbuf = (bf16*)(ws + 4096 + 8388608);       // [2048][4096]

    float* outf = (float*)d_out;           // [2048][4096] fp32  Output 0
    float* Kof  = outf + 8388608;          // [2048][8][128] fp32 Output 1 (MFMA path)
    float* Vof  = outf + 10485760;         // [2048][8][128] fp32 Output 2 (naive)
    bf16*  qb   = (bf16*)d_out;            // bf16 q scratch in out's first 16 MiB

    detect_convert<<<1, 256, 0, stream>>>((const unsigned short*)Wq, qw, kw, flag, qwc, kwc);

    // --- Output 1: MFMA gemm_nt -> norm_rope(fp32) -> Kof
    gemm_nt<<<dim3(8, 16), 256, 0, stream>>>(x, Wk, kqm, flag, 0, 2048, 4096, 1024, 1024, 0);
    norm_rope<<<4096, 256, 0, stream>>>(kqm, nullptr, Kof, kwc, positions, 8);

    // --- Output 2 + attention V: naive v -> fp32 Vof only
    naive_gemm<<<dim3(64, 128), 256, 0, stream>>>(x, Wv, nullptr, Vof, flag, 0, 4096, 4096, 1024, 1024);

    // --- Output 0: naive q/k -> attn -> out projection
    naive_gemm<<<dim3(256, 128), 256, 0, stream>>>(x, Wq, qb, nullptr, flag, 0, 4096, 4096, 4096, 4096);
    naive_gemm<<<dim3(64, 128),  256, 0, stream>>>(x, Wk, kraw, nullptr, flag, 0, 4096, 4096, 1024, 1024);
    norm_rope<<<16384, 256, 0, stream>>>(qb, qb, nullptr, qwc, positions, 32);       // q in-place bf16
    norm_rope<<<4096, 256, 0, stream>>>(kraw, kraw, nullptr, kwc, positions, 8);     // naive k bf16 (attn input)
    // attention reads naive k (bf16) ... use kraw for Q-path independence from Output 1
    naive_attn<<<16384, 256, 0, stream>>>(qb, Kof, Vof, attnbuf);
    naive_gemm<<<dim3(256, 128), 256, 0, stream>>>(attnbuf, Wo, nullptr, outf, flag, 1, 4096, 4096, 4096, 4096);
}